// Round 10
// baseline (73.850 us; speedup 1.0000x reference)
//
#include <hip/hip_runtime.h>

#define D 64
#define CHARSET 128
#define GAMMA 1.0f
#define SPW 16          // segments per wave
#define HROWS 8         // packed hist rows per wave (2 segs/word)
#define HPADW 132       // padded row length in words
#define NP 12           // prefetched 64-char batches (768 chars)

typedef short s8v __attribute__((ext_vector_type(8)));   // bf16x8
typedef float f4v __attribute__((ext_vector_type(4)));   // fp32x4 accum

__device__ __forceinline__ short f32_to_bf16(float f) {
    unsigned u = __builtin_bit_cast(unsigned, f);
    unsigned r = (u + 0x7FFFu + ((u >> 16) & 1u)) >> 16;   // RNE
    return (short)r;
}

// Fused preproc: segstart[s] (s in [0,n_seg_pad]) + bf16 transposed table
__global__ void preproc(const int* __restrict__ seg, const float* __restrict__ emb,
                        int total, int n_seg_pad,
                        int* __restrict__ segstart, unsigned short* __restrict__ tabT) {
    int q = blockIdx.x * blockDim.x + threadIdx.x;
    if (q < D * CHARSET) {
        int d = q >> 7, k = q & 127;
        tabT[q] = (unsigned short)f32_to_bf16(emb[k * D + d]);
    }
    int c0 = q * 4;
    if (c0 >= total) return;
    int v[4];
    if (c0 + 3 < total) { int4 w = *(const int4*)&seg[c0]; v[0]=w.x; v[1]=w.y; v[2]=w.z; v[3]=w.w; }
    else { for (int i = 0; i < 4; ++i) v[i] = (c0 + i < total) ? seg[c0 + i] : v[i>0?i-1:0]; }
    int prev = (c0 == 0) ? -1 : seg[c0 - 1];
    int lim = min(4, total - c0);
    for (int i = 0; i < lim; ++i) {
        int cur = v[i];
        for (int s = prev + 1; s <= cur; ++s) segstart[s] = c0 + i;
        if (c0 + i == total - 1)
            for (int s = cur + 1; s <= n_seg_pad; ++s) segstart[s] = total;
        prev = cur;
    }
}

__global__ void init_out(float* out, float v) {
    if (threadIdx.x == 0 && blockIdx.x == 0) out[0] = v;
}

// in-wave cooperative lower_bound (fallback only)
__device__ __forceinline__ int lower_bound64(const int* __restrict__ seg,
                                             int lo, int hi, int target, int lane) {
    while (hi - lo > 64) {
        int step = (hi - lo) >> 6;
        int idx = lo + lane * step;
        int v = seg[idx];
        unsigned long long mask = __ballot(v < target);
        if (mask == 0ull) { hi = lo; break; }
        int k = 63 - __clzll(mask);
        int nhi = (k == 63) ? hi : (lo + (k + 1) * step);
        lo = lo + k * step; hi = nhi;
    }
    if (hi > lo) {
        int idx = lo + lane;
        int v = (idx < hi) ? seg[idx] : 0x7FFFFFFF;
        lo += __popcll(__ballot(v < target));
    }
    return lo;
}

template<bool USE_WS>
__global__ __launch_bounds__(256) void attr_wave_kernel(
    const int* __restrict__ char_ids,
    const int* __restrict__ seg_ids,            // fallback only
    const int* __restrict__ head_ids,
    const int* __restrict__ rel_ids,
    const float* __restrict__ char_emb,
    const float* __restrict__ rel_emb,
    const float* __restrict__ ent_emb,
    const unsigned short* __restrict__ tabT,    // bf16 [dim][k]
    const int* __restrict__ segstart,
    float* __restrict__ partials,
    int* __restrict__ counter,
    float* __restrict__ out, float base,
    int n_triples, int total_chars, int nwaves)
{
    __shared__ __align__(16) unsigned hist[4][HROWS * HPADW];  // 16.9 KB
    __shared__ int isLast;
    __shared__ float red2[4];

    const int wib   = threadIdx.x >> 6;
    const int lane  = threadIdx.x & 63;
    const int gwave = blockIdx.x * 4 + wib;
    const bool active = gwave < nwaves;

    if (active) {
        const int s0 = __builtin_amdgcn_readfirstlane(gwave * SPW);
        unsigned* hq = hist[wib];
        const int col = lane & 15, g4 = lane >> 4;

        // ---- issue id loads first ----
        int hid[4], rid[4];
        #pragma unroll
        for (int j = 0; j < 4; ++j) {
            int s = s0 + g4 * 4 + j;
            bool v = s < n_triples;
            hid[j] = v ? head_ids[s] : 0;
            rid[j] = v ? rel_ids[s]  : 0;
        }

        // ---- wave-uniform boundaries (consecutive -> s_loads) ----
        int b[SPW + 1];
        int cbg, ce;
        if (USE_WS) {
            #pragma unroll
            for (int j = 0; j <= SPW; ++j) b[j] = segstart[s0 + j];
            cbg = b[0]; ce = b[SPW];
        } else {
            cbg = lower_bound64(seg_ids, 0, total_chars, s0, lane);
            ce  = lower_bound64(seg_ids, cbg, total_chars,
                                min(s0 + SPW, n_triples), lane);
        }

        // ---- zero own hist quarter (LDS pipe, overlaps loads) ----
        for (int i = lane; i < HROWS * HPADW / 4; i += 64)
            ((uint4*)hq)[i] = make_uint4(0u, 0u, 0u, 0u);

        // ---- prefetch h gathers: independent of hist, hidden under it ----
        float hv[16];
        #pragma unroll
        for (int reg = 0; reg < 4; ++reg)
            #pragma unroll
            for (int ct = 0; ct < 4; ++ct)
                hv[reg * 4 + ct] = ent_emb[(size_t)hid[reg] * D + ct * 16 + col];

        // ---- histogram ----
        if (USE_WS) {
            // prefetch 12 batches of char ids, then classify+atomic
            int idp[NP];
            #pragma unroll
            for (int u = 0; u < NP; ++u) {
                int c = cbg + u * 64 + lane;
                idp[u] = (c < ce) ? char_ids[c] : -1;
            }
            #pragma unroll
            for (int u = 0; u < NP; ++u) {
                if (idp[u] >= 0) {
                    int c = cbg + u * 64 + lane;
                    int sid = 0;
                    #pragma unroll
                    for (int j = 1; j <= SPW; ++j) sid += (c >= b[j]) ? 1 : 0;
                    atomicAdd(&hq[(sid >> 1) * HPADW + idp[u]], 1u << ((sid & 1) << 4));
                }
            }
            for (int c0 = cbg + NP * 64; c0 < ce; c0 += 64) {   // rare tail
                int c = c0 + lane;
                if (c < ce) {
                    int id = char_ids[c];
                    int sid = 0;
                    #pragma unroll
                    for (int j = 1; j <= SPW; ++j) sid += (c >= b[j]) ? 1 : 0;
                    atomicAdd(&hq[(sid >> 1) * HPADW + id], 1u << ((sid & 1) << 4));
                }
            }
        } else {
            for (int c = cbg + lane; c < ce; c += 64) {
                int sa = seg_ids[c], da = char_ids[c];
                unsigned oa = (unsigned)(sa - s0);
                atomicAdd(&hq[(oa >> 1) * HPADW + da], 1u << ((oa & 1u) << 4));
            }
        }

        // ---- C[16 seg][64 dim] = hist x emb via 16 x mfma_16x16x32_bf16 ----
        f4v acc[4] = {(f4v)0.f, (f4v)0.f, (f4v)0.f, (f4v)0.f};
        const int prow = col >> 1;
        const unsigned sh = (col & 1u) << 4;
        #pragma unroll 1
        for (int st = 0; st < 4; ++st) {
            int kbase = st * 32 + g4 * 8;
            uint4 c0 = *(const uint4*)&hq[prow * HPADW + kbase];
            uint4 c1 = *(const uint4*)&hq[prow * HPADW + kbase + 4];
            s8v afrag;
            afrag[0] = f32_to_bf16((float)((c0.x >> sh) & 0xFFFFu));
            afrag[1] = f32_to_bf16((float)((c0.y >> sh) & 0xFFFFu));
            afrag[2] = f32_to_bf16((float)((c0.z >> sh) & 0xFFFFu));
            afrag[3] = f32_to_bf16((float)((c0.w >> sh) & 0xFFFFu));
            afrag[4] = f32_to_bf16((float)((c1.x >> sh) & 0xFFFFu));
            afrag[5] = f32_to_bf16((float)((c1.y >> sh) & 0xFFFFu));
            afrag[6] = f32_to_bf16((float)((c1.z >> sh) & 0xFFFFu));
            afrag[7] = f32_to_bf16((float)((c1.w >> sh) & 0xFFFFu));
            #pragma unroll
            for (int ct = 0; ct < 4; ++ct) {
                s8v bfrag;
                if (USE_WS) {
                    bfrag = *(const s8v*)&tabT[(size_t)(ct * 16 + col) * CHARSET + kbase];
                } else {
                    #pragma unroll
                    for (int e = 0; e < 8; ++e)
                        bfrag[e] = f32_to_bf16(char_emb[(kbase + e) * D + ct * 16 + col]);
                }
                acc[ct] = __builtin_amdgcn_mfma_f32_16x16x32_bf16(afrag, bfrag, acc[ct], 0, 0, 0);
            }
        }

        // ---- epilogue: |h + r - t| using prefetched hv ----
        float part = 0.f;
        #pragma unroll
        for (int reg = 0; reg < 4; ++reg) {
            int s = s0 + g4 * 4 + reg;
            if (s < n_triples) {
                const float* rp = &rel_emb[rid[reg] * D];   // 5.6 KB table: L1
                #pragma unroll
                for (int ct = 0; ct < 4; ++ct)
                    part += fabsf(hv[reg * 4 + ct] + rp[ct * 16 + col] - acc[ct][reg]);
            }
        }

        #pragma unroll
        for (int off = 32; off > 0; off >>= 1)
            part += __shfl_down(part, off, 64);
        if (lane == 0) {
            if (USE_WS)
                __hip_atomic_store(&partials[gwave], part,
                                   __ATOMIC_RELAXED, __HIP_MEMORY_SCOPE_AGENT);
            else
                atomicAdd(out, part);
        }
    }

    if (USE_WS) {
        // ---- last-block-done final reduction (deterministic order) ----
        __syncthreads();
        if (threadIdx.x == 0) {
            __threadfence();
            isLast = (atomicAdd(counter, 1) == gridDim.x - 1) ? 1 : 0;
        }
        __syncthreads();
        if (isLast) {                      // block-uniform
            __threadfence();
            float a = 0.f;
            for (int i = threadIdx.x; i < nwaves; i += 256)
                a += __hip_atomic_load(&partials[i],
                                       __ATOMIC_RELAXED, __HIP_MEMORY_SCOPE_AGENT);
            #pragma unroll
            for (int off = 32; off > 0; off >>= 1)
                a += __shfl_down(a, off, 64);
            if ((threadIdx.x & 63) == 0) red2[threadIdx.x >> 6] = a;
            __syncthreads();
            if (threadIdx.x == 0)
                out[0] = base + red2[0] + red2[1] + red2[2] + red2[3];
        }
    }
}

extern "C" void kernel_launch(void* const* d_in, const int* in_sizes, int n_in,
                              void* d_out, int out_size, void* d_ws, size_t ws_size,
                              hipStream_t stream) {
    const int*   char_ids = (const int*)  d_in[0];
    const int*   seg_ids  = (const int*)  d_in[1];
    const int*   head_ids = (const int*)  d_in[2];
    const int*   rel_ids  = (const int*)  d_in[3];
    const float* char_emb = (const float*)d_in[4];
    const float* rel_emb  = (const float*)d_in[5];
    const float* ent_emb  = (const float*)d_in[6];
    float* out = (float*)d_out;

    const int total_chars = in_sizes[0];
    const int n_triples   = in_sizes[2];
    const int nwaves    = (n_triples + SPW - 1) / SPW;
    const int nblocks   = (nwaves + 3) / 4;
    const int n_seg_pad = nwaves * SPW;
    const float base = (float)n_triples * GAMMA;

    // ws: tabT bf16[8192] | segstart int[n_seg_pad+1] | partials float[nwaves] | counter
    unsigned short* tabT = (unsigned short*)d_ws;
    int*   segstart = (int*)((char*)d_ws + D * CHARSET * sizeof(unsigned short));
    float* partials = (float*)(segstart + n_seg_pad + 1);
    int*   counter  = (int*)(partials + nwaves);
    const size_t need = D * CHARSET * 2 + (size_t)(n_seg_pad + 2 + nwaves) * 4;

    if (ws_size >= need) {
        hipMemsetAsync(counter, 0, sizeof(int), stream);
        const int pthreads = (total_chars + 3) / 4;
        preproc<<<(pthreads + 255) / 256, 256, 0, stream>>>(
            seg_ids, char_emb, total_chars, n_seg_pad, segstart, tabT);
        attr_wave_kernel<true><<<nblocks, 256, 0, stream>>>(
            char_ids, seg_ids, head_ids, rel_ids,
            char_emb, rel_emb, ent_emb, tabT, segstart,
            partials, counter, out, base,
            n_triples, total_chars, nwaves);
    } else {
        init_out<<<1, 64, 0, stream>>>(out, base);
        attr_wave_kernel<false><<<nblocks, 256, 0, stream>>>(
            char_ids, seg_ids, head_ids, rel_ids,
            char_emb, rel_emb, ent_emb, nullptr, nullptr,
            nullptr, nullptr, out, base,
            n_triples, total_chars, nwaves);
    }
}

// Round 11
// 42.146 us; speedup vs baseline: 1.7523x; 1.7523x over previous
//
#include <hip/hip_runtime.h>

#define D 64
#define CHARSET 128
#define GAMMA 1.0f
#define SPW 16          // segments per wave
#define HROWS 8         // packed hist rows per wave (2 segs/word)
#define HPADW 132       // padded row length in words

typedef short s8v __attribute__((ext_vector_type(8)));   // bf16x8
typedef float f4v __attribute__((ext_vector_type(4)));   // fp32x4 accum

__device__ __forceinline__ short f32_to_bf16(float f) {
    unsigned u = __builtin_bit_cast(unsigned, f);
    unsigned r = (u + 0x7FFFu + ((u >> 16) & 1u)) >> 16;   // RNE
    return (short)r;
}

// Fused preproc: segstart[s] (s in [0,n_seg_pad]) + bf16 transposed table
__global__ void preproc(const int* __restrict__ seg, const float* __restrict__ emb,
                        int total, int n_seg_pad,
                        int* __restrict__ segstart, unsigned short* __restrict__ tabT) {
    int q = blockIdx.x * blockDim.x + threadIdx.x;
    if (q < D * CHARSET) {
        int d = q >> 7, k = q & 127;
        tabT[q] = (unsigned short)f32_to_bf16(emb[k * D + d]);
    }
    int c0 = q * 4;
    if (c0 >= total) return;
    int v[4];
    if (c0 + 3 < total) { int4 w = *(const int4*)&seg[c0]; v[0]=w.x; v[1]=w.y; v[2]=w.z; v[3]=w.w; }
    else { for (int i = 0; i < 4; ++i) v[i] = (c0 + i < total) ? seg[c0 + i] : v[i>0?i-1:0]; }
    int prev = (c0 == 0) ? -1 : seg[c0 - 1];
    int lim = min(4, total - c0);
    for (int i = 0; i < lim; ++i) {
        int cur = v[i];
        for (int s = prev + 1; s <= cur; ++s) segstart[s] = c0 + i;
        if (c0 + i == total - 1)
            for (int s = cur + 1; s <= n_seg_pad; ++s) segstart[s] = total;
        prev = cur;
    }
}

__global__ void reduce_partials(const float* __restrict__ p, int n,
                                float* __restrict__ out, float base) {
    __shared__ float red[16];
    float acc = 0.f;
    int nt4 = n >> 2;
    const float4* p4 = (const float4*)p;
    for (int i = threadIdx.x; i < nt4; i += 1024) { float4 v = p4[i]; acc += v.x + v.y + v.z + v.w; }
    for (int i = (nt4 << 2) + threadIdx.x; i < n; i += 1024) acc += p[i];
    #pragma unroll
    for (int off = 32; off > 0; off >>= 1) acc += __shfl_down(acc, off, 64);
    int wid = threadIdx.x >> 6, lane = threadIdx.x & 63;
    if (lane == 0) red[wid] = acc;
    __syncthreads();
    if (threadIdx.x == 0) { float s = base; for (int i = 0; i < 16; ++i) s += red[i]; out[0] = s; }
}

__global__ void init_out(float* out, float v) {
    if (threadIdx.x == 0 && blockIdx.x == 0) out[0] = v;
}

// in-wave cooperative lower_bound (fallback only)
__device__ __forceinline__ int lower_bound64(const int* __restrict__ seg,
                                             int lo, int hi, int target, int lane) {
    while (hi - lo > 64) {
        int step = (hi - lo) >> 6;
        int idx = lo + lane * step;
        int v = seg[idx];
        unsigned long long mask = __ballot(v < target);
        if (mask == 0ull) { hi = lo; break; }
        int k = 63 - __clzll(mask);
        int nhi = (k == 63) ? hi : (lo + (k + 1) * step);
        lo = lo + k * step; hi = nhi;
    }
    if (hi > lo) {
        int idx = lo + lane;
        int v = (idx < hi) ? seg[idx] : 0x7FFFFFFF;
        lo += __popcll(__ballot(v < target));
    }
    return lo;
}

// Barrier-free: each wave owns SPW=16 segments end-to-end.
template<bool USE_WS>
__global__ __launch_bounds__(256) void attr_wave_kernel(
    const int* __restrict__ char_ids,
    const int* __restrict__ seg_ids,            // fallback only
    const int* __restrict__ head_ids,
    const int* __restrict__ rel_ids,
    const float* __restrict__ char_emb,
    const float* __restrict__ rel_emb,
    const float* __restrict__ ent_emb,
    const unsigned short* __restrict__ tabT,    // bf16 [dim][k], USE_WS only
    const int* __restrict__ segstart,           // USE_WS only
    float* __restrict__ partials,               // USE_WS: per-wave slot; else out
    int n_triples, int total_chars, int nwaves)
{
    __shared__ __align__(16) unsigned hist[4][HROWS * HPADW];  // 16.9 KB

    const int wib   = threadIdx.x >> 6;
    const int lane  = threadIdx.x & 63;
    const int gwave = blockIdx.x * 4 + wib;
    if (gwave >= nwaves) return;

    const int s0 = __builtin_amdgcn_readfirstlane(gwave * SPW);
    unsigned* hq = hist[wib];

    // zero own hist quarter (wave-private)
    for (int i = lane; i < HROWS * HPADW / 4; i += 64)
        ((uint4*)hq)[i] = make_uint4(0u, 0u, 0u, 0u);

    // head/rel ids for my 4 output rows (row = (lane>>4)*4 + j)
    const int col = lane & 15, g4 = lane >> 4;
    int hid[4], rid[4];
    #pragma unroll
    for (int j = 0; j < 4; ++j) {
        int s = s0 + g4 * 4 + j;
        hid[j] = (s < n_triples) ? head_ids[s] : 0;
        rid[j] = (s < n_triples) ? rel_ids[s] : 0;
    }

    if (USE_WS) {
        // ---- 17 wave-uniform boundaries -> SGPRs ----
        int b[SPW + 1];
        #pragma unroll
        for (int j = 0; j <= SPW; ++j) b[j] = segstart[s0 + j];
        const int cbg = b[0], ce = b[SPW];

        // ---- hist: int4-vectorized char stream (256 chars / wave-iter),
        //      hand-pipelined 2-deep; branchless classify vs SGPR bounds ----
        // window starts at enclosing 4-aligned addr; reads stay in-bounds
        // (w0 % 4 == 0 and total_chars % 4 == 0 => w0+3 < total_chars).
        int w0 = (cbg & ~3) + lane * 4;
        int4 cur = (w0 < ce) ? *(const int4*)&char_ids[w0]
                             : make_int4(0, 0, 0, 0);
        while (w0 < ce) {
            int w1 = w0 + 256;
            int4 nxt = (w1 < ce) ? *(const int4*)&char_ids[w1]
                                 : make_int4(0, 0, 0, 0);
            #pragma unroll
            for (int e = 0; e < 4; ++e) {
                int c = w0 + e;
                if (c >= cbg && c < ce) {
                    int cid = (&cur.x)[e];
                    int sid = 0;
                    #pragma unroll
                    for (int j = 1; j < SPW; ++j) sid += (c >= b[j]) ? 1 : 0;
                    atomicAdd(&hq[(sid >> 1) * HPADW + cid], 1u << ((sid & 1) << 4));
                }
            }
            cur = nxt; w0 = w1;
        }
    } else {
        int cb = lower_bound64(seg_ids, 0, total_chars, s0, lane);
        int ce = lower_bound64(seg_ids, cb, total_chars,
                               min(s0 + SPW, n_triples), lane);
        for (int c = cb + lane; c < ce; c += 64) {
            int sa = seg_ids[c], da = char_ids[c];
            unsigned oa = (unsigned)(sa - s0);
            atomicAdd(&hq[(oa >> 1) * HPADW + da], 1u << ((oa & 1u) << 4));
        }
    }
    // same-wave RAW on LDS: in-wave ds ordering, no barrier needed

    // ---- C[16 seg][64 dim] = hist x emb via 16 x mfma_16x16x32_bf16 ----
    // A: row=lane&15, k=(lane>>4)*8+e.  B: col=lane&15, k=(lane>>4)*8+e.
    // C: col=lane&15, row=(lane>>4)*4+reg.
    f4v acc[4] = {(f4v)0.f, (f4v)0.f, (f4v)0.f, (f4v)0.f};
    const int prow = col >> 1;
    const unsigned sh = (col & 1u) << 4;
    #pragma unroll 1
    for (int st = 0; st < 4; ++st) {
        int kbase = st * 32 + g4 * 8;
        uint4 c0 = *(const uint4*)&hq[prow * HPADW + kbase];
        uint4 c1 = *(const uint4*)&hq[prow * HPADW + kbase + 4];
        s8v afrag;
        afrag[0] = f32_to_bf16((float)((c0.x >> sh) & 0xFFFFu));
        afrag[1] = f32_to_bf16((float)((c0.y >> sh) & 0xFFFFu));
        afrag[2] = f32_to_bf16((float)((c0.z >> sh) & 0xFFFFu));
        afrag[3] = f32_to_bf16((float)((c0.w >> sh) & 0xFFFFu));
        afrag[4] = f32_to_bf16((float)((c1.x >> sh) & 0xFFFFu));
        afrag[5] = f32_to_bf16((float)((c1.y >> sh) & 0xFFFFu));
        afrag[6] = f32_to_bf16((float)((c1.z >> sh) & 0xFFFFu));
        afrag[7] = f32_to_bf16((float)((c1.w >> sh) & 0xFFFFu));
        #pragma unroll
        for (int ct = 0; ct < 4; ++ct) {
            s8v bfrag;
            if (USE_WS) {
                bfrag = *(const s8v*)&tabT[(size_t)(ct * 16 + col) * CHARSET + kbase];
            } else {
                #pragma unroll
                for (int e = 0; e < 8; ++e)
                    bfrag[e] = f32_to_bf16(char_emb[(kbase + e) * D + ct * 16 + col]);
            }
            acc[ct] = __builtin_amdgcn_mfma_f32_16x16x32_bf16(afrag, bfrag, acc[ct], 0, 0, 0);
        }
    }

    // ---- epilogue: part += |h + r - t| ----
    float part = 0.f;
    #pragma unroll
    for (int reg = 0; reg < 4; ++reg) {
        int s = s0 + g4 * 4 + reg;
        if (s < n_triples) {
            const float* hp = &ent_emb[(size_t)hid[reg] * D];
            const float* rp = &rel_emb[rid[reg] * D];
            #pragma unroll
            for (int ct = 0; ct < 4; ++ct) {
                int dim = ct * 16 + col;
                part += fabsf(hp[dim] + rp[dim] - acc[ct][reg]);
            }
        }
    }

    // ---- wave reduce -> per-wave slot ----
    #pragma unroll
    for (int off = 32; off > 0; off >>= 1)
        part += __shfl_down(part, off, 64);
    if (lane == 0) {
        if (USE_WS) partials[gwave] = part;
        else        atomicAdd(partials, part);
    }
}

extern "C" void kernel_launch(void* const* d_in, const int* in_sizes, int n_in,
                              void* d_out, int out_size, void* d_ws, size_t ws_size,
                              hipStream_t stream) {
    const int*   char_ids = (const int*)  d_in[0];
    const int*   seg_ids  = (const int*)  d_in[1];
    const int*   head_ids = (const int*)  d_in[2];
    const int*   rel_ids  = (const int*)  d_in[3];
    const float* char_emb = (const float*)d_in[4];
    const float* rel_emb  = (const float*)d_in[5];
    const float* ent_emb  = (const float*)d_in[6];
    float* out = (float*)d_out;

    const int total_chars = in_sizes[0];
    const int n_triples   = in_sizes[2];
    const int nwaves   = (n_triples + SPW - 1) / SPW;
    const int nblocks  = (nwaves + 3) / 4;
    const int n_seg_pad = nwaves * SPW;            // segstart[0..n_seg_pad]
    const float base = (float)n_triples * GAMMA;

    // ws layout: tabT bf16[8192] | segstart int[n_seg_pad+1] | partials float[nwaves]
    unsigned short* tabT = (unsigned short*)d_ws;
    int*   segstart = (int*)((char*)d_ws + D * CHARSET * sizeof(unsigned short));
    float* partials = (float*)(segstart + n_seg_pad + 1);
    const size_t need = D * CHARSET * 2 + (size_t)(n_seg_pad + 1 + nwaves) * 4;

    if (ws_size >= need) {
        const int pthreads = (total_chars + 3) / 4;
        preproc<<<(pthreads + 255) / 256, 256, 0, stream>>>(
            seg_ids, char_emb, total_chars, n_seg_pad, segstart, tabT);
        attr_wave_kernel<true><<<nblocks, 256, 0, stream>>>(
            char_ids, seg_ids, head_ids, rel_ids,
            char_emb, rel_emb, ent_emb, tabT, segstart, partials,
            n_triples, total_chars, nwaves);
        reduce_partials<<<1, 1024, 0, stream>>>(partials, nwaves, out, base);
    } else {
        init_out<<<1, 64, 0, stream>>>(out, base);
        attr_wave_kernel<false><<<nblocks, 256, 0, stream>>>(
            char_ids, seg_ids, head_ids, rel_ids,
            char_emb, rel_emb, ent_emb, nullptr, nullptr, out,
            n_triples, total_chars, nwaves);
    }
}

// Round 12
// 41.143 us; speedup vs baseline: 1.7950x; 1.0244x over previous
//
#include <hip/hip_runtime.h>

#define D 64
#define CHARSET 128
#define GAMMA 1.0f
#define SPW 16          // segments per wave (= per block)
#define HROWS 8         // packed hist rows (2 segs/word)
#define HPADW 132       // padded row length in words
#define NSLOT 3         // prefetched int4 slots/lane = 768 chars (+5 sigma)

typedef short s8v __attribute__((ext_vector_type(8)));   // bf16x8
typedef float f4v __attribute__((ext_vector_type(4)));   // fp32x4 accum

__device__ __forceinline__ short f32_to_bf16(float f) {
    unsigned u = __builtin_bit_cast(unsigned, f);
    unsigned r = (u + 0x7FFFu + ((u >> 16) & 1u)) >> 16;   // RNE
    return (short)r;
}

// Fused preproc: segstart[s] (s in [0,n_seg_pad]) + bf16 transposed table
__global__ void preproc(const int* __restrict__ seg, const float* __restrict__ emb,
                        int total, int n_seg_pad,
                        int* __restrict__ segstart, unsigned short* __restrict__ tabT) {
    int q = blockIdx.x * blockDim.x + threadIdx.x;
    if (q < D * CHARSET) {
        int d = q >> 7, k = q & 127;
        tabT[q] = (unsigned short)f32_to_bf16(emb[k * D + d]);
    }
    int c0 = q * 4;
    if (c0 >= total) return;
    int v[4];
    if (c0 + 3 < total) { int4 w = *(const int4*)&seg[c0]; v[0]=w.x; v[1]=w.y; v[2]=w.z; v[3]=w.w; }
    else { for (int i = 0; i < 4; ++i) v[i] = (c0 + i < total) ? seg[c0 + i] : v[i>0?i-1:0]; }
    int prev = (c0 == 0) ? -1 : seg[c0 - 1];
    int lim = min(4, total - c0);
    for (int i = 0; i < lim; ++i) {
        int cur = v[i];
        for (int s = prev + 1; s <= cur; ++s) segstart[s] = c0 + i;
        if (c0 + i == total - 1)
            for (int s = cur + 1; s <= n_seg_pad; ++s) segstart[s] = total;
        prev = cur;
    }
}

__global__ void reduce_partials(const float* __restrict__ p, int n,
                                float* __restrict__ out, float base) {
    __shared__ float red[16];
    float acc = 0.f;
    int nt4 = n >> 2;
    const float4* p4 = (const float4*)p;
    for (int i = threadIdx.x; i < nt4; i += 1024) { float4 v = p4[i]; acc += v.x + v.y + v.z + v.w; }
    for (int i = (nt4 << 2) + threadIdx.x; i < n; i += 1024) acc += p[i];
    #pragma unroll
    for (int off = 32; off > 0; off >>= 1) acc += __shfl_down(acc, off, 64);
    int wid = threadIdx.x >> 6, lane = threadIdx.x & 63;
    if (lane == 0) red[wid] = acc;
    __syncthreads();
    if (threadIdx.x == 0) { float s = base; for (int i = 0; i < 16; ++i) s += red[i]; out[0] = s; }
}

__global__ void init_out(float* out, float v) {
    if (threadIdx.x == 0 && blockIdx.x == 0) out[0] = v;
}

// in-wave cooperative lower_bound (fallback only)
__device__ __forceinline__ int lower_bound64(const int* __restrict__ seg,
                                             int lo, int hi, int target, int lane) {
    while (hi - lo > 64) {
        int step = (hi - lo) >> 6;
        int idx = lo + lane * step;
        int v = seg[idx];
        unsigned long long mask = __ballot(v < target);
        if (mask == 0ull) { hi = lo; break; }
        int k = 63 - __clzll(mask);
        int nhi = (k == 63) ? hi : (lo + (k + 1) * step);
        lo = lo + k * step; hi = nhi;
    }
    if (hi > lo) {
        int idx = lo + lane;
        int v = (idx < hi) ? seg[idx] : 0x7FFFFFFF;
        lo += __popcll(__ballot(v < target));
    }
    return lo;
}

// One wave per block; all independent loads issued up-front and pinned.
template<bool USE_WS>
__global__ __launch_bounds__(64, 4) void attr_wave_kernel(
    const int* __restrict__ char_ids,
    const int* __restrict__ seg_ids,            // fallback only
    const int* __restrict__ head_ids,
    const int* __restrict__ rel_ids,
    const float* __restrict__ char_emb,
    const float* __restrict__ rel_emb,
    const float* __restrict__ ent_emb,
    const unsigned short* __restrict__ tabT,    // bf16 [dim][k], USE_WS only
    const int* __restrict__ segstart,           // USE_WS only
    float* __restrict__ partials,               // USE_WS: per-wave slot; else out
    int n_triples, int total_chars, int nwaves)
{
    __shared__ __align__(16) unsigned hq[HROWS * HPADW];   // 4.2 KB, wave-private

    const int lane  = threadIdx.x;          // 0..63
    const int gwave = blockIdx.x;
    const int s0  = gwave * SPW;
    const int col = lane & 15, g4 = lane >> 4;

    // ---- (1) id loads: first in vmcnt FIFO ----
    int hid[4], rid[4];
    #pragma unroll
    for (int j = 0; j < 4; ++j) {
        int s = s0 + g4 * 4 + j;
        bool v = s < n_triples;
        hid[j] = v ? head_ids[s] : 0;
        rid[j] = v ? rel_ids[s]  : 0;
    }

    float hv[16];
    f4v acc[4] = {(f4v)0.f, (f4v)0.f, (f4v)0.f, (f4v)0.f};

    if (USE_WS) {
        // ---- (2) boundaries: wave-uniform -> scalar loads ----
        int b[SPW + 1];
        #pragma unroll
        for (int j = 0; j <= SPW; ++j) b[j] = segstart[s0 + j];
        const int cbg = b[0], ce = b[SPW];

        // ---- (3) char stream: all NSLOT int4 loads issued, clamped ----
        const int wbase = cbg & ~3;
        const int wmax  = total_chars - 4;
        int4 slot[NSLOT];
        #pragma unroll
        for (int u = 0; u < NSLOT; ++u) {
            int w = wbase + u * 256 + lane * 4;
            slot[u] = *(const int4*)&char_ids[min(w, wmax)];
        }

        // ---- (4) h-gathers: stay in flight through the whole hist phase ----
        #pragma unroll
        for (int r = 0; r < 4; ++r)
            #pragma unroll
            for (int ct = 0; ct < 4; ++ct)
                hv[r * 4 + ct] = ent_emb[(size_t)hid[r] * D + ct * 16 + col];
        __builtin_amdgcn_sched_barrier(0);   // pin issue order of (1)-(4)

        // ---- (5) zero hist (LDS pipe; global loads still in flight) ----
        #pragma unroll
        for (int i = 0; i < 5; ++i) {
            int idx = i * 64 + lane;
            if (idx < HROWS * HPADW / 4)
                ((uint4*)hq)[idx] = make_uint4(0u, 0u, 0u, 0u);
        }

        // ---- (6) classify + atomic; consumes slots in FIFO order ----
        #pragma unroll
        for (int u = 0; u < NSLOT; ++u) {
            int w = wbase + u * 256 + lane * 4;
            #pragma unroll
            for (int e = 0; e < 4; ++e) {
                int c = w + e;
                if (c >= cbg && c < ce) {
                    int cid = (&slot[u].x)[e];
                    int sid = 0;
                    #pragma unroll
                    for (int j = 1; j < SPW; ++j) sid += (c >= b[j]) ? 1 : 0;
                    atomicAdd(&hq[(sid >> 1) * HPADW + cid], 1u << ((sid & 1) << 4));
                }
            }
        }
        for (int w = wbase + NSLOT * 256 + lane * 4; w < ce; w += 256) {  // rare tail
            int4 cur = *(const int4*)&char_ids[w];
            #pragma unroll
            for (int e = 0; e < 4; ++e) {
                int c = w + e;
                if (c < ce) {
                    int cid = (&cur.x)[e];
                    int sid = 0;
                    #pragma unroll
                    for (int j = 1; j < SPW; ++j) sid += (c >= b[j]) ? 1 : 0;
                    atomicAdd(&hq[(sid >> 1) * HPADW + cid], 1u << ((sid & 1) << 4));
                }
            }
        }
    } else {
        for (int i = lane; i < HROWS * HPADW / 4; i += 64)
            ((uint4*)hq)[i] = make_uint4(0u, 0u, 0u, 0u);
        int cb = lower_bound64(seg_ids, 0, total_chars, s0, lane);
        int ce = lower_bound64(seg_ids, cb, total_chars,
                               min(s0 + SPW, n_triples), lane);
        for (int c = cb + lane; c < ce; c += 64) {
            int sa = seg_ids[c], da = char_ids[c];
            unsigned oa = (unsigned)(sa - s0);
            atomicAdd(&hq[(oa >> 1) * HPADW + da], 1u << ((oa & 1u) << 4));
        }
        #pragma unroll
        for (int r = 0; r < 4; ++r)
            #pragma unroll
            for (int ct = 0; ct < 4; ++ct)
                hv[r * 4 + ct] = ent_emb[(size_t)hid[r] * D + ct * 16 + col];
    }
    // same-wave RAW on LDS: in-wave ds ordering, no barrier needed

    // ---- (7) C[16 seg][64 dim] = hist x emb via 16 x mfma_16x16x32_bf16 ----
    // A: row=lane&15, k=(lane>>4)*8+e.  B: col=lane&15, k=(lane>>4)*8+e.
    // C: col=lane&15, row=(lane>>4)*4+reg.
    const int prow = col >> 1;
    const unsigned sh = (col & 1u) << 4;
    #pragma unroll 1
    for (int st = 0; st < 4; ++st) {
        int kbase = st * 32 + g4 * 8;
        uint4 c0 = *(const uint4*)&hq[prow * HPADW + kbase];
        uint4 c1 = *(const uint4*)&hq[prow * HPADW + kbase + 4];
        s8v afrag;
        afrag[0] = f32_to_bf16((float)((c0.x >> sh) & 0xFFFFu));
        afrag[1] = f32_to_bf16((float)((c0.y >> sh) & 0xFFFFu));
        afrag[2] = f32_to_bf16((float)((c0.z >> sh) & 0xFFFFu));
        afrag[3] = f32_to_bf16((float)((c0.w >> sh) & 0xFFFFu));
        afrag[4] = f32_to_bf16((float)((c1.x >> sh) & 0xFFFFu));
        afrag[5] = f32_to_bf16((float)((c1.y >> sh) & 0xFFFFu));
        afrag[6] = f32_to_bf16((float)((c1.z >> sh) & 0xFFFFu));
        afrag[7] = f32_to_bf16((float)((c1.w >> sh) & 0xFFFFu));
        #pragma unroll
        for (int ct = 0; ct < 4; ++ct) {
            s8v bfrag;
            if (USE_WS) {
                bfrag = *(const s8v*)&tabT[(size_t)(ct * 16 + col) * CHARSET + kbase];
            } else {
                #pragma unroll
                for (int e = 0; e < 8; ++e)
                    bfrag[e] = f32_to_bf16(char_emb[(kbase + e) * D + ct * 16 + col]);
            }
            acc[ct] = __builtin_amdgcn_mfma_f32_16x16x32_bf16(afrag, bfrag, acc[ct], 0, 0, 0);
        }
    }

    // ---- (8) epilogue: |h + r - t| with prefetched hv ----
    float part = 0.f;
    #pragma unroll
    for (int r = 0; r < 4; ++r) {
        int s = s0 + g4 * 4 + r;
        if (s < n_triples) {
            const float* rp = &rel_emb[rid[r] * D];    // 5.6 KB table: cache-hot
            #pragma unroll
            for (int ct = 0; ct < 4; ++ct)
                part += fabsf(hv[r * 4 + ct] + rp[ct * 16 + col] - acc[ct][r]);
        }
    }

    // ---- (9) wave reduce -> per-wave slot ----
    #pragma unroll
    for (int off = 32; off > 0; off >>= 1)
        part += __shfl_down(part, off, 64);
    if (lane == 0) {
        if (USE_WS) partials[gwave] = part;
        else        atomicAdd(partials, part);
    }
}

extern "C" void kernel_launch(void* const* d_in, const int* in_sizes, int n_in,
                              void* d_out, int out_size, void* d_ws, size_t ws_size,
                              hipStream_t stream) {
    const int*   char_ids = (const int*)  d_in[0];
    const int*   seg_ids  = (const int*)  d_in[1];
    const int*   head_ids = (const int*)  d_in[2];
    const int*   rel_ids  = (const int*)  d_in[3];
    const float* char_emb = (const float*)d_in[4];
    const float* rel_emb  = (const float*)d_in[5];
    const float* ent_emb  = (const float*)d_in[6];
    float* out = (float*)d_out;

    const int total_chars = in_sizes[0];
    const int n_triples   = in_sizes[2];
    const int nwaves    = (n_triples + SPW - 1) / SPW;
    const int n_seg_pad = nwaves * SPW;
    const float base = (float)n_triples * GAMMA;

    // ws layout: tabT bf16[8192] | segstart int[n_seg_pad+1] | partials float[nwaves]
    unsigned short* tabT = (unsigned short*)d_ws;
    int*   segstart = (int*)((char*)d_ws + D * CHARSET * sizeof(unsigned short));
    float* partials = (float*)(segstart + n_seg_pad + 1);
    const size_t need = D * CHARSET * 2 + (size_t)(n_seg_pad + 1 + nwaves) * 4;

    if (ws_size >= need) {
        const int pthreads = (total_chars + 3) / 4;
        preproc<<<(pthreads + 255) / 256, 256, 0, stream>>>(
            seg_ids, char_emb, total_chars, n_seg_pad, segstart, tabT);
        attr_wave_kernel<true><<<nwaves, 64, 0, stream>>>(
            char_ids, seg_ids, head_ids, rel_ids,
            char_emb, rel_emb, ent_emb, tabT, segstart, partials,
            n_triples, total_chars, nwaves);
        reduce_partials<<<1, 1024, 0, stream>>>(partials, nwaves, out, base);
    } else {
        init_out<<<1, 64, 0, stream>>>(out, base);
        attr_wave_kernel<false><<<nwaves, 64, 0, stream>>>(
            char_ids, seg_ids, head_ids, rel_ids,
            char_emb, rel_emb, ent_emb, nullptr, nullptr, out,
            n_triples, total_chars, nwaves);
    }
}